// Round 8
// baseline (141.937 us; speedup 1.0000x reference)
//
#include <hip/hip_runtime.h>

// Problem constants (from reference)
#define T_LEN   4096
#define BKB     256            // B_ENV * K_OPT (batch lanes)
#define OBSD    3
#define NCHUNK  512            // time chunks == grid size
#define TC      (T_LEN / NCHUNK)   // 8 steps per chunk
#define CH      (NCHUNK * BKB) // elements per summary array (131072)
#define TOT     (T_LEN * BKB)  // elements per output tensor
#define EPSF    1e-5f
#define HALFC   (NCHUNK / 2)   // 256 chunk-pairs for the scan

// ws float layout (total 5*CH*4B = 2.62 MB + 16B barrier):
//   [0, CH)      A_c    per-chunk decay product,   TRANSPOSED [lane][chunk]
//   [CH, 2CH)    B0_c   per-chunk affine offset 0, [lane][chunk]
//   [2CH, 3CH)   B1_c   per-chunk affine offset 1, [lane][chunk]
//   [3CH, 4CH)   s0_in  incoming state ch 0,       [chunk][lane]
//   [4CH, 5CH)   s1_in  incoming state ch 1,       [chunk][lane]
//   [5CH..]      4 ints: {cnt1, flag1, cnt2, flag2} (memset to 0 each call)

// ---- fast math helpers ----
__device__ __forceinline__ float sigmoid_f(float x) {
    return __builtin_amdgcn_rcpf(1.0f + __expf(-x));
}
__device__ __forceinline__ float silu_f(float x) { return x * sigmoid_f(x); }
__device__ __forceinline__ float softplus_f(float x) {
    return x > 15.0f ? x : __logf(1.0f + __expf(x));
}

// ---- hand-rolled grid barrier (all blocks provably co-resident) ----
__device__ __forceinline__ void grid_barrier(int* cnt, int* flag, int nblk) {
    __syncthreads();                       // drains this block's vmem (vmcnt(0))
    if (threadIdx.x == 0) {
        int prev = __hip_atomic_fetch_add(cnt, 1, __ATOMIC_ACQ_REL,
                                          __HIP_MEMORY_SCOPE_AGENT);
        if (prev == nblk - 1) {
            __hip_atomic_store(flag, 1, __ATOMIC_RELEASE,
                               __HIP_MEMORY_SCOPE_AGENT);
        } else {
            while (__hip_atomic_load(flag, __ATOMIC_ACQUIRE,
                                     __HIP_MEMORY_SCOPE_AGENT) == 0) {
                __builtin_amdgcn_s_sleep(2);
            }
        }
    }
    __syncthreads();
}

// ---- per-thread parameter block (all uniform; compiler scalarizes) ----
struct Pars {
    float Wi[6];    // W_in (2,3) row-major
    float bi[2];
    float Wp[14];   // W_inproj (7,2) row-major
    float cw0[4], cw1[4], cb[4];   // conv_w (4,2), conv_b
    float dtb;      // dt_bias[0]
    float A;        // -exp(A_log[0])
};

__device__ __forceinline__ Pars load_pars(const float* W_in, const float* b_in,
                                          const float* W_inproj, const float* conv_w,
                                          const float* conv_b, const float* dt_bias,
                                          const float* A_log) {
    Pars p;
#pragma unroll
    for (int i = 0; i < 6; ++i) p.Wi[i] = W_in[i];
    p.bi[0] = b_in[0]; p.bi[1] = b_in[1];
#pragma unroll
    for (int i = 0; i < 14; ++i) p.Wp[i] = W_inproj[i];
#pragma unroll
    for (int k = 0; k < 4; ++k) {
        p.cw0[k] = conv_w[2 * k];
        p.cw1[k] = conv_w[2 * k + 1];
        p.cb[k]  = conv_b[k];
    }
    p.dtb = dt_bias[0];
    p.A   = -__expf(A_log[0]);
    return p;
}

struct Step {
    float a, b0, b1;     // state update s = a*s + b
    float Cv, xh0, xh1;  // C and silu'd x
    float z0, z1;        // gate pre-activations
};

__device__ __forceinline__ Step do_step(const Pars& p, float o0, float o1, float o2,
                                        float pp[4]) {
    float x0 = fmaf(p.Wi[2], o2, fmaf(p.Wi[1], o1, fmaf(p.Wi[0], o0, p.bi[0])));
    float x1 = fmaf(p.Wi[5], o2, fmaf(p.Wi[4], o1, fmaf(p.Wi[3], o0, p.bi[1])));
    float z0 = fmaf(p.Wp[1], x1, p.Wp[0] * x0);
    float z1 = fmaf(p.Wp[3], x1, p.Wp[2] * x0);
    float q0 = fmaf(p.Wp[5], x1, p.Wp[4] * x0);
    float q1 = fmaf(p.Wp[7], x1, p.Wp[6] * x0);
    float q2 = fmaf(p.Wp[9], x1, p.Wp[8] * x0);
    float q3 = fmaf(p.Wp[11], x1, p.Wp[10] * x0);
    float dtr = fmaf(p.Wp[13], x1, fmaf(p.Wp[12], x0, p.dtb));
    float dt = softplus_f(dtr);
    float c0 = fmaf(pp[0], p.cw0[0], fmaf(q0, p.cw1[0], p.cb[0]));
    float c1 = fmaf(pp[1], p.cw0[1], fmaf(q1, p.cw1[1], p.cb[1]));
    float c2 = fmaf(pp[2], p.cw0[2], fmaf(q2, p.cw1[2], p.cb[2]));
    float c3 = fmaf(pp[3], p.cw0[3], fmaf(q3, p.cw1[3], p.cb[3]));
    pp[0] = q0; pp[1] = q1; pp[2] = q2; pp[3] = q3;
    float xh0 = silu_f(c0);
    float xh1 = silu_f(c1);
    float Bv  = silu_f(c2);
    float Cv  = silu_f(c3);
    float a = __expf(p.A * dt);
    Step s;
    s.a = a;
    float xd0 = xh0 * dt, xd1 = xh1 * dt;
    s.b0 = Bv * xd0; s.b1 = Bv * xd1;
    s.Cv = Cv; s.xh0 = xh0; s.xh1 = xh1; s.z0 = z0; s.z1 = z1;
    return s;
}

// pre-conv xBC at t0-1 (zeros if t0==0, matching the reference's zero pad)
__device__ __forceinline__ void init_pp(const Pars& p, const float* __restrict__ obs,
                                        int t0, int b, float pp[4]) {
    if (t0 == 0) { pp[0] = pp[1] = pp[2] = pp[3] = 0.0f; return; }
    const float* op = obs + ((size_t)(t0 - 1) * BKB + b) * OBSD;
    float o0 = op[0], o1 = op[1], o2 = op[2];
    float x0 = fmaf(p.Wi[2], o2, fmaf(p.Wi[1], o1, fmaf(p.Wi[0], o0, p.bi[0])));
    float x1 = fmaf(p.Wi[5], o2, fmaf(p.Wi[4], o1, fmaf(p.Wi[3], o0, p.bi[1])));
    pp[0] = fmaf(p.Wp[5], x1, p.Wp[4] * x0);
    pp[1] = fmaf(p.Wp[7], x1, p.Wp[6] * x0);
    pp[2] = fmaf(p.Wp[9], x1, p.Wp[8] * x0);
    pp[3] = fmaf(p.Wp[11], x1, p.Wp[10] * x0);
}

__global__ __launch_bounds__(BKB, 2) void k_fused(
    const float* __restrict__ obs, const float* __restrict__ W_in,
    const float* __restrict__ b_in, const float* __restrict__ W_inproj,
    const float* __restrict__ conv_w, const float* __restrict__ conv_b,
    const float* __restrict__ dt_bias, const float* __restrict__ A_log,
    const float* __restrict__ Dp_, const float* __restrict__ norm_w,
    const float* __restrict__ W_out, const float* __restrict__ head,
    const float* __restrict__ log_tau, float* __restrict__ ws,
    float* __restrict__ out) {
    __shared__ float sA[HALFC], sB0[HALFC], sB1[HALFC];

    const int b  = threadIdx.x;   // batch lane (phases A, C)
    const int c  = blockIdx.x;    // time chunk (phases A, C)
    const int t0 = c * TC;
    int* bar = (int*)(ws + 5 * (size_t)CH);

    Pars p = load_pars(W_in, b_in, W_inproj, conv_w, conv_b, dt_bias, A_log);
    const float Dp = Dp_[0];
    const float w0 = (W_out[0] + W_out[2]) * norm_w[0];
    const float w1 = (W_out[1] + W_out[3]) * norm_w[1];
    const float hscale = softplus_f(head[0]);
    const float itau   = __expf(-log_tau[0]);

    // ---------- Phase A: chunk summaries, stores transposed [lane][chunk] --
    {
        float pp[4];
        init_pp(p, obs, t0, b, pp);
        float Aa = 1.0f, Ba0 = 0.0f, Ba1 = 0.0f;
#pragma unroll
        for (int i = 0; i < TC; ++i) {
            const float* op = obs + ((size_t)(t0 + i) * BKB + b) * OBSD;
            Step s = do_step(p, op[0], op[1], op[2], pp);
            Aa  *= s.a;
            Ba0 = fmaf(s.a, Ba0, s.b0);
            Ba1 = fmaf(s.a, Ba1, s.b1);
        }
        size_t tbase = (size_t)b * NCHUNK + c;
        ws[tbase]          = Aa;
        ws[CH + tbase]     = Ba0;
        ws[2 * CH + tbase] = Ba1;
    }

    grid_barrier(bar + 0, bar + 1, NCHUNK);

    // ---------- Phase B: per-lane scan (blocks 0..255), thread = chunk-pair -
    if (c < BKB) {
        const int lane = c;
        const int i    = b;               // pair index 0..255
        const size_t pbase = (size_t)lane * NCHUNK + 2 * i;
        float2 Av  = *(const float2*)(ws + pbase);            // coalesced
        float2 B0v = *(const float2*)(ws + CH + pbase);
        float2 B1v = *(const float2*)(ws + 2 * CH + pbase);
        // pair compose: m(2i+1) ∘ m(2i)
        float Ap  = Av.y * Av.x;
        float Bp0 = fmaf(Av.y, B0v.x, B0v.y);
        float Bp1 = fmaf(Av.y, B1v.x, B1v.y);
        float A = Ap, B0 = Bp0, B1 = Bp1;
        sA[i] = A; sB0[i] = B0; sB1[i] = B1;
        __syncthreads();
#pragma unroll
        for (int off = 1; off < HALFC; off <<= 1) {
            float pA = 1.0f, pB0 = 0.0f, pB1 = 0.0f;
            if (i >= off) { pA = sA[i - off]; pB0 = sB0[i - off]; pB1 = sB1[i - off]; }
            __syncthreads();
            B0 = fmaf(A, pB0, B0);
            B1 = fmaf(A, pB1, B1);
            A  = A * pA;
            sA[i] = A; sB0[i] = B0; sB1[i] = B1;
            __syncthreads();
        }
        // exclusive prefix for pair i = inclusive[i-1] (identity at i=0)
        float e0 = (i > 0) ? sB0[i - 1] : 0.0f;
        float e1 = (i > 0) ? sB1[i - 1] : 0.0f;
        // s_in for chunk 2i, then chunk 2i+1 = m(2i) applied to it
        ws[3 * CH + (size_t)(2 * i) * BKB + lane]     = e0;
        ws[4 * CH + (size_t)(2 * i) * BKB + lane]     = e1;
        ws[3 * CH + (size_t)(2 * i + 1) * BKB + lane] = fmaf(Av.x, e0, B0v.x);
        ws[4 * CH + (size_t)(2 * i + 1) * BKB + lane] = fmaf(Av.x, e1, B1v.x);
    }

    grid_barrier(bar + 2, bar + 3, NCHUNK);

    // ---------- Phase C: recompute steps with true state, write outputs ----
    {
        float s0 = ws[3 * CH + (size_t)c * BKB + b];          // coalesced
        float s1 = ws[4 * CH + (size_t)c * BKB + b];
        float pp[4];
        init_pp(p, obs, t0, b, pp);
#pragma unroll
        for (int i = 0; i < TC; ++i) {
            const int t = t0 + i;
            const float* op = obs + ((size_t)t * BKB + b) * OBSD;
            Step s = do_step(p, op[0], op[1], op[2], pp);
            s0 = fmaf(s.a, s0, s.b0);
            s1 = fmaf(s.a, s1, s.b1);
            float y0 = fmaf(s.Cv, s0, s.xh0 * Dp);
            float y1 = fmaf(s.Cv, s1, s.xh1 * Dp);
            y0 *= silu_f(s.z0);
            y1 *= silu_f(s.z1);
            float r = __builtin_amdgcn_rsqf(fmaf(0.5f, y0 * y0 + y1 * y1, EPSF));
            float q = (w0 * y0 + w1 * y1) * r * hscale;
            out[(size_t)t * BKB + b]       = q;
            out[TOT + (size_t)t * BKB + b] = q * itau;
        }
    }
}

extern "C" void kernel_launch(void* const* d_in, const int* in_sizes, int n_in,
                              void* d_out, int out_size, void* d_ws, size_t ws_size,
                              hipStream_t stream) {
    const float* obs      = (const float*)d_in[0];
    const float* W_in     = (const float*)d_in[1];
    const float* b_in     = (const float*)d_in[2];
    const float* W_inproj = (const float*)d_in[3];
    const float* conv_w   = (const float*)d_in[4];
    const float* conv_b   = (const float*)d_in[5];
    const float* dt_bias  = (const float*)d_in[6];
    const float* A_log    = (const float*)d_in[7];
    const float* Dp       = (const float*)d_in[8];
    const float* norm_w   = (const float*)d_in[9];
    const float* W_out    = (const float*)d_in[10];
    const float* head     = (const float*)d_in[11];
    const float* log_tau  = (const float*)d_in[12];
    // d_in[13] = k (unused in compute)

    float* ws  = (float*)d_ws;   // needs 5*CH*4 + 16 bytes
    float* out = (float*)d_out;

    // zero the 4 barrier ints (graph-capturable async memset, deterministic)
    hipMemsetAsync(ws + 5 * (size_t)CH, 0, 4 * sizeof(int), stream);

    k_fused<<<NCHUNK, BKB, 0, stream>>>(obs, W_in, b_in, W_inproj, conv_w, conv_b,
                                        dt_bias, A_log, Dp, norm_w, W_out, head,
                                        log_tau, ws, out);
}

// Round 9
// 23.673 us; speedup vs baseline: 5.9957x; 5.9957x over previous
//
#include <hip/hip_runtime.h>

// Problem constants (from reference)
#define T_LEN   4096
#define BKB     256            // B_ENV * K_OPT (batch lanes)
#define OBSD    3
#define NCHUNK  512            // time chunks
#define TC      (T_LEN / NCHUNK)   // 8 steps per chunk
#define NPAIR   (NCHUNK / 2)   // 256 chunk-pairs = scan block size
#define TOT     (T_LEN * BKB)  // elements per output tensor
#define EPSF    1e-5f

// ws layout:
//   float4 sum[NCHUNK*BKB] : {A,B0,B1,_} at [chunk][lane]  (2 MB, offset 0)
//   float2 sin[BKB*NCHUNK] : {s0,s1}     at [lane][chunk]  (1 MB, offset 2 MB)
#define SUM_ELEMS ((size_t)NCHUNK * BKB)

// ---- fast math helpers ----
__device__ __forceinline__ float sigmoid_f(float x) {
    return __builtin_amdgcn_rcpf(1.0f + __expf(-x));
}
__device__ __forceinline__ float silu_f(float x) { return x * sigmoid_f(x); }
__device__ __forceinline__ float softplus_f(float x) {
    return x > 15.0f ? x : __logf(1.0f + __expf(x));
}

// ---- per-thread parameter block (all uniform; compiler scalarizes) ----
struct Pars {
    float Wi[6];    // W_in (2,3) row-major
    float bi[2];
    float Wp[14];   // W_inproj (7,2) row-major
    float cw0[4], cw1[4], cb[4];   // conv_w (4,2), conv_b
    float dtb;      // dt_bias[0]
    float A;        // -exp(A_log[0])
};

__device__ __forceinline__ Pars load_pars(const float* W_in, const float* b_in,
                                          const float* W_inproj, const float* conv_w,
                                          const float* conv_b, const float* dt_bias,
                                          const float* A_log) {
    Pars p;
#pragma unroll
    for (int i = 0; i < 6; ++i) p.Wi[i] = W_in[i];
    p.bi[0] = b_in[0]; p.bi[1] = b_in[1];
#pragma unroll
    for (int i = 0; i < 14; ++i) p.Wp[i] = W_inproj[i];
#pragma unroll
    for (int k = 0; k < 4; ++k) {
        p.cw0[k] = conv_w[2 * k];
        p.cw1[k] = conv_w[2 * k + 1];
        p.cb[k]  = conv_b[k];
    }
    p.dtb = dt_bias[0];
    p.A   = -__expf(A_log[0]);
    return p;
}

struct Step {
    float a, b0, b1;     // state update s = a*s + b
    float Cv, xh0, xh1;  // C and silu'd x
    float z0, z1;        // gate pre-activations
};

__device__ __forceinline__ Step do_step(const Pars& p, float o0, float o1, float o2,
                                        float pp[4]) {
    float x0 = fmaf(p.Wi[2], o2, fmaf(p.Wi[1], o1, fmaf(p.Wi[0], o0, p.bi[0])));
    float x1 = fmaf(p.Wi[5], o2, fmaf(p.Wi[4], o1, fmaf(p.Wi[3], o0, p.bi[1])));
    float z0 = fmaf(p.Wp[1], x1, p.Wp[0] * x0);
    float z1 = fmaf(p.Wp[3], x1, p.Wp[2] * x0);
    float q0 = fmaf(p.Wp[5], x1, p.Wp[4] * x0);
    float q1 = fmaf(p.Wp[7], x1, p.Wp[6] * x0);
    float q2 = fmaf(p.Wp[9], x1, p.Wp[8] * x0);
    float q3 = fmaf(p.Wp[11], x1, p.Wp[10] * x0);
    float dtr = fmaf(p.Wp[13], x1, fmaf(p.Wp[12], x0, p.dtb));
    float dt = softplus_f(dtr);
    float c0 = fmaf(pp[0], p.cw0[0], fmaf(q0, p.cw1[0], p.cb[0]));
    float c1 = fmaf(pp[1], p.cw0[1], fmaf(q1, p.cw1[1], p.cb[1]));
    float c2 = fmaf(pp[2], p.cw0[2], fmaf(q2, p.cw1[2], p.cb[2]));
    float c3 = fmaf(pp[3], p.cw0[3], fmaf(q3, p.cw1[3], p.cb[3]));
    pp[0] = q0; pp[1] = q1; pp[2] = q2; pp[3] = q3;
    float xh0 = silu_f(c0);
    float xh1 = silu_f(c1);
    float Bv  = silu_f(c2);
    float Cv  = silu_f(c3);
    float a = __expf(p.A * dt);
    Step s;
    s.a = a;
    float xd0 = xh0 * dt, xd1 = xh1 * dt;
    s.b0 = Bv * xd0; s.b1 = Bv * xd1;
    s.Cv = Cv; s.xh0 = xh0; s.xh1 = xh1; s.z0 = z0; s.z1 = z1;
    return s;
}

// pre-conv xBC at t0-1 (zeros if t0==0, matching the reference's zero pad)
__device__ __forceinline__ void init_pp(const Pars& p, const float* __restrict__ obs,
                                        int t0, int b, float pp[4]) {
    if (t0 == 0) { pp[0] = pp[1] = pp[2] = pp[3] = 0.0f; return; }
    const float* op = obs + ((size_t)(t0 - 1) * BKB + b) * OBSD;
    float o0 = op[0], o1 = op[1], o2 = op[2];
    float x0 = fmaf(p.Wi[2], o2, fmaf(p.Wi[1], o1, fmaf(p.Wi[0], o0, p.bi[0])));
    float x1 = fmaf(p.Wi[5], o2, fmaf(p.Wi[4], o1, fmaf(p.Wi[3], o0, p.bi[1])));
    pp[0] = fmaf(p.Wp[5], x1, p.Wp[4] * x0);
    pp[1] = fmaf(p.Wp[7], x1, p.Wp[6] * x0);
    pp[2] = fmaf(p.Wp[9], x1, p.Wp[8] * x0);
    pp[3] = fmaf(p.Wp[11], x1, p.Wp[10] * x0);
}

// Kernel 1: per-(chunk, lane) affine summary -> coalesced float4 [chunk][lane]
__global__ __launch_bounds__(BKB) void k_summary(
    const float* __restrict__ obs, const float* __restrict__ W_in,
    const float* __restrict__ b_in, const float* __restrict__ W_inproj,
    const float* __restrict__ conv_w, const float* __restrict__ conv_b,
    const float* __restrict__ dt_bias, const float* __restrict__ A_log,
    float4* __restrict__ sum) {
    int b = threadIdx.x;
    int c = blockIdx.x;
    int t0 = c * TC;
    Pars p = load_pars(W_in, b_in, W_inproj, conv_w, conv_b, dt_bias, A_log);
    float pp[4];
    init_pp(p, obs, t0, b, pp);
    float Aa = 1.0f, Ba0 = 0.0f, Ba1 = 0.0f;
#pragma unroll
    for (int i = 0; i < TC; ++i) {
        const float* op = obs + ((size_t)(t0 + i) * BKB + b) * OBSD;
        Step s = do_step(p, op[0], op[1], op[2], pp);
        Aa  *= s.a;
        Ba0 = fmaf(s.a, Ba0, s.b0);
        Ba1 = fmaf(s.a, Ba1, s.b1);
    }
    sum[(size_t)c * BKB + b] = make_float4(Aa, Ba0, Ba1, 0.0f);
}

// Kernel 2: per-lane scan, barrier-free wave-shuffle version.
// block = lane (256 blocks), thread = chunk-pair (256 threads).
// 2 scattered 16B loads/thread (L3-shared), shuffle scan, ONE LDS exchange,
// fully coalesced float4 s_in stores in [lane][chunk] order.
__global__ __launch_bounds__(NPAIR) void k_scan(const float4* __restrict__ sum,
                                                float2* __restrict__ sin_) {
    __shared__ float wtA[4], wtB0[4], wtB1[4];
    const int L  = blockIdx.x;
    const int i  = threadIdx.x;       // pair index: chunks 2i, 2i+1
    const int wl = i & 63;
    const int w  = i >> 6;

    float4 m0 = sum[(size_t)(2 * i) * BKB + L];
    float4 m1 = sum[(size_t)(2 * i + 1) * BKB + L];
    // pair compose: m1 ∘ m0   (A' = A1*A0, B' = A1*B0 + B1)
    float A  = m1.x * m0.x;
    float B0 = fmaf(m1.x, m0.y, m1.y);
    float B1 = fmaf(m1.x, m0.z, m1.z);

    // inclusive scan within wave (6 shuffle-compose steps, no barriers)
#pragma unroll
    for (int off = 1; off < 64; off <<= 1) {
        float pA  = __shfl_up(A,  off, 64);
        float pB0 = __shfl_up(B0, off, 64);
        float pB1 = __shfl_up(B1, off, 64);
        if (wl >= off) {
            B0 = fmaf(A, pB0, B0);   // cur ∘ prev
            B1 = fmaf(A, pB1, B1);
            A  = A * pA;
        }
    }
    if (wl == 63) { wtA[w] = A; wtB0[w] = B0; wtB1[w] = B1; }
    __syncthreads();
    // prefix of earlier waves (ascending compose), identity for wave 0
    float wpA = 1.0f, wpB0 = 0.0f, wpB1 = 0.0f;
#pragma unroll
    for (int ww = 0; ww < 3; ++ww) {
        if (ww < w) {
            float a = wtA[ww];
            wpB0 = fmaf(a, wpB0, wtB0[ww]);
            wpB1 = fmaf(a, wpB1, wtB1[ww]);
            wpA  = a * wpA;
        }
    }
    // full inclusive = own-wave-inclusive ∘ wave_prefix
    float iA  = A * wpA;
    float iB0 = fmaf(A, wpB0, B0);
    float iB1 = fmaf(A, wpB1, B1);
    // exclusive[i] = inclusive[i-1]
    float eB0 = __shfl_up(iB0, 1, 64);
    float eB1 = __shfl_up(iB1, 1, 64);
    if (wl == 0) { eB0 = wpB0; eB1 = wpB1; }
    (void)iA;
    // s_in(chunk 2i)   = exclusive applied to s=0  -> (eB0, eB1)
    // s_in(chunk 2i+1) = m(2i) ∘ exclusive applied to 0
    float s10 = fmaf(m0.x, eB0, m0.y);
    float s11 = fmaf(m0.x, eB1, m0.z);
    float2* dst = sin_ + (size_t)L * NCHUNK + 2 * i;   // coalesced float4/thread
    dst[0] = make_float2(eB0, eB1);
    dst[1] = make_float2(s10, s11);
}

// Kernel 3: read incoming state (scattered 8B load, L3-shared), recompute the
// chunk's steps, write q & logits coalesced.
__global__ __launch_bounds__(BKB) void k_apply(
    const float* __restrict__ obs, const float* __restrict__ W_in,
    const float* __restrict__ b_in, const float* __restrict__ W_inproj,
    const float* __restrict__ conv_w, const float* __restrict__ conv_b,
    const float* __restrict__ dt_bias, const float* __restrict__ A_log,
    const float* __restrict__ Dp_, const float* __restrict__ norm_w,
    const float* __restrict__ W_out, const float* __restrict__ head,
    const float* __restrict__ log_tau, const float2* __restrict__ sin_,
    float* __restrict__ out) {
    int b = threadIdx.x;
    int c = blockIdx.x;
    int t0 = c * TC;
    // issue the scattered state load first so it overlaps the uniform setup
    float2 sv = sin_[(size_t)b * NCHUNK + c];
    Pars p = load_pars(W_in, b_in, W_inproj, conv_w, conv_b, dt_bias, A_log);
    const float Dp = Dp_[0];
    const float w0 = (W_out[0] + W_out[2]) * norm_w[0];
    const float w1 = (W_out[1] + W_out[3]) * norm_w[1];
    const float hscale = softplus_f(head[0]);
    const float itau   = __expf(-log_tau[0]);

    float s0 = sv.x, s1 = sv.y;
    float pp[4];
    init_pp(p, obs, t0, b, pp);
#pragma unroll
    for (int i = 0; i < TC; ++i) {
        const int t = t0 + i;
        const float* op = obs + ((size_t)t * BKB + b) * OBSD;
        Step s = do_step(p, op[0], op[1], op[2], pp);
        s0 = fmaf(s.a, s0, s.b0);
        s1 = fmaf(s.a, s1, s.b1);
        float y0 = fmaf(s.Cv, s0, s.xh0 * Dp);
        float y1 = fmaf(s.Cv, s1, s.xh1 * Dp);
        y0 *= silu_f(s.z0);
        y1 *= silu_f(s.z1);
        float r = __builtin_amdgcn_rsqf(fmaf(0.5f, y0 * y0 + y1 * y1, EPSF));
        float q = (w0 * y0 + w1 * y1) * r * hscale;
        out[(size_t)t * BKB + b]       = q;
        out[TOT + (size_t)t * BKB + b] = q * itau;
    }
}

extern "C" void kernel_launch(void* const* d_in, const int* in_sizes, int n_in,
                              void* d_out, int out_size, void* d_ws, size_t ws_size,
                              hipStream_t stream) {
    const float* obs      = (const float*)d_in[0];
    const float* W_in     = (const float*)d_in[1];
    const float* b_in     = (const float*)d_in[2];
    const float* W_inproj = (const float*)d_in[3];
    const float* conv_w   = (const float*)d_in[4];
    const float* conv_b   = (const float*)d_in[5];
    const float* dt_bias  = (const float*)d_in[6];
    const float* A_log    = (const float*)d_in[7];
    const float* Dp       = (const float*)d_in[8];
    const float* norm_w   = (const float*)d_in[9];
    const float* W_out    = (const float*)d_in[10];
    const float* head     = (const float*)d_in[11];
    const float* log_tau  = (const float*)d_in[12];
    // d_in[13] = k (unused in compute)

    float4* sum  = (float4*)d_ws;                         // 2 MB
    float2* sin_ = (float2*)((char*)d_ws + SUM_ELEMS * sizeof(float4)); // 1 MB
    float*  out  = (float*)d_out;

    k_summary<<<NCHUNK, BKB, 0, stream>>>(obs, W_in, b_in, W_inproj, conv_w, conv_b,
                                          dt_bias, A_log, sum);
    k_scan<<<BKB, NPAIR, 0, stream>>>(sum, sin_);
    k_apply<<<NCHUNK, BKB, 0, stream>>>(obs, W_in, b_in, W_inproj, conv_w, conv_b,
                                        dt_bias, A_log, Dp, norm_w, W_out, head,
                                        log_tau, sin_, out);
}

// Round 10
// 19.706 us; speedup vs baseline: 7.2028x; 1.2013x over previous
//
#include <hip/hip_runtime.h>

// Problem constants (from reference)
#define T_LEN   4096
#define BKB     256            // B_ENV * K_OPT (batch lanes)
#define OBSD    3
#define NCHUNK  256            // time chunks
#define TC      (T_LEN / NCHUNK)   // 16 steps per chunk
#define SCANT   64             // scan threads per block (1 wave)
#define FOLD    (NCHUNK / SCANT)   // 4 chunks per scan thread
#define TOT     (T_LEN * BKB)  // elements per output tensor
#define EPSF    1e-5f

// ws layout:
//   float4 sum[BKB*NCHUNK] : {A,B0,B1,_} at [lane][chunk]  (1 MB, offset 0)
//   float2 sin[BKB*NCHUNK] : {s0,s1}     at [lane][chunk]  (0.5 MB after)
#define SUM_ELEMS ((size_t)BKB * NCHUNK)

// ---- fast math helpers ----
__device__ __forceinline__ float sigmoid_f(float x) {
    return __builtin_amdgcn_rcpf(1.0f + __expf(-x));
}
__device__ __forceinline__ float silu_f(float x) { return x * sigmoid_f(x); }
__device__ __forceinline__ float softplus_f(float x) {
    return x > 15.0f ? x : __logf(1.0f + __expf(x));
}

// ---- per-thread parameter block (all uniform; compiler scalarizes) ----
struct Pars {
    float Wi[6];    // W_in (2,3) row-major
    float bi[2];
    float Wp[14];   // W_inproj (7,2) row-major
    float cw0[4], cw1[4], cb[4];   // conv_w (4,2), conv_b
    float dtb;      // dt_bias[0]
    float A;        // -exp(A_log[0])
};

__device__ __forceinline__ Pars load_pars(const float* W_in, const float* b_in,
                                          const float* W_inproj, const float* conv_w,
                                          const float* conv_b, const float* dt_bias,
                                          const float* A_log) {
    Pars p;
#pragma unroll
    for (int i = 0; i < 6; ++i) p.Wi[i] = W_in[i];
    p.bi[0] = b_in[0]; p.bi[1] = b_in[1];
#pragma unroll
    for (int i = 0; i < 14; ++i) p.Wp[i] = W_inproj[i];
#pragma unroll
    for (int k = 0; k < 4; ++k) {
        p.cw0[k] = conv_w[2 * k];
        p.cw1[k] = conv_w[2 * k + 1];
        p.cb[k]  = conv_b[k];
    }
    p.dtb = dt_bias[0];
    p.A   = -__expf(A_log[0]);
    return p;
}

struct Step {
    float a, b0, b1;     // state update s = a*s + b
    float Cv, xh0, xh1;  // C and silu'd x
    float z0, z1;        // gate pre-activations
};

__device__ __forceinline__ Step do_step(const Pars& p, float o0, float o1, float o2,
                                        float pp[4]) {
    float x0 = fmaf(p.Wi[2], o2, fmaf(p.Wi[1], o1, fmaf(p.Wi[0], o0, p.bi[0])));
    float x1 = fmaf(p.Wi[5], o2, fmaf(p.Wi[4], o1, fmaf(p.Wi[3], o0, p.bi[1])));
    float z0 = fmaf(p.Wp[1], x1, p.Wp[0] * x0);
    float z1 = fmaf(p.Wp[3], x1, p.Wp[2] * x0);
    float q0 = fmaf(p.Wp[5], x1, p.Wp[4] * x0);
    float q1 = fmaf(p.Wp[7], x1, p.Wp[6] * x0);
    float q2 = fmaf(p.Wp[9], x1, p.Wp[8] * x0);
    float q3 = fmaf(p.Wp[11], x1, p.Wp[10] * x0);
    float dtr = fmaf(p.Wp[13], x1, fmaf(p.Wp[12], x0, p.dtb));
    float dt = softplus_f(dtr);
    float c0 = fmaf(pp[0], p.cw0[0], fmaf(q0, p.cw1[0], p.cb[0]));
    float c1 = fmaf(pp[1], p.cw0[1], fmaf(q1, p.cw1[1], p.cb[1]));
    float c2 = fmaf(pp[2], p.cw0[2], fmaf(q2, p.cw1[2], p.cb[2]));
    float c3 = fmaf(pp[3], p.cw0[3], fmaf(q3, p.cw1[3], p.cb[3]));
    pp[0] = q0; pp[1] = q1; pp[2] = q2; pp[3] = q3;
    float xh0 = silu_f(c0);
    float xh1 = silu_f(c1);
    float Bv  = silu_f(c2);
    float Cv  = silu_f(c3);
    float a = __expf(p.A * dt);
    Step s;
    s.a = a;
    float xd0 = xh0 * dt, xd1 = xh1 * dt;
    s.b0 = Bv * xd0; s.b1 = Bv * xd1;
    s.Cv = Cv; s.xh0 = xh0; s.xh1 = xh1; s.z0 = z0; s.z1 = z1;
    return s;
}

// pre-conv xBC at t0-1 (zeros if t0==0, matching the reference's zero pad)
__device__ __forceinline__ void init_pp(const Pars& p, const float* __restrict__ obs,
                                        int t0, int b, float pp[4]) {
    if (t0 == 0) { pp[0] = pp[1] = pp[2] = pp[3] = 0.0f; return; }
    const float* op = obs + ((size_t)(t0 - 1) * BKB + b) * OBSD;
    float o0 = op[0], o1 = op[1], o2 = op[2];
    float x0 = fmaf(p.Wi[2], o2, fmaf(p.Wi[1], o1, fmaf(p.Wi[0], o0, p.bi[0])));
    float x1 = fmaf(p.Wi[5], o2, fmaf(p.Wi[4], o1, fmaf(p.Wi[3], o0, p.bi[1])));
    pp[0] = fmaf(p.Wp[5], x1, p.Wp[4] * x0);
    pp[1] = fmaf(p.Wp[7], x1, p.Wp[6] * x0);
    pp[2] = fmaf(p.Wp[9], x1, p.Wp[8] * x0);
    pp[3] = fmaf(p.Wp[11], x1, p.Wp[10] * x0);
}

// Kernel 1: per-(chunk, lane) affine summary -> float4 at [lane][chunk]
// (scattered stores, latency-insensitive; K2's loads become contiguous).
__global__ __launch_bounds__(BKB) void k_summary(
    const float* __restrict__ obs, const float* __restrict__ W_in,
    const float* __restrict__ b_in, const float* __restrict__ W_inproj,
    const float* __restrict__ conv_w, const float* __restrict__ conv_b,
    const float* __restrict__ dt_bias, const float* __restrict__ A_log,
    float4* __restrict__ sum) {
    int b = threadIdx.x;
    int c = blockIdx.x;
    int t0 = c * TC;
    Pars p = load_pars(W_in, b_in, W_inproj, conv_w, conv_b, dt_bias, A_log);
    float pp[4];
    init_pp(p, obs, t0, b, pp);
    float Aa = 1.0f, Ba0 = 0.0f, Ba1 = 0.0f;
#pragma unroll
    for (int i = 0; i < TC; ++i) {
        const float* op = obs + ((size_t)(t0 + i) * BKB + b) * OBSD;
        Step s = do_step(p, op[0], op[1], op[2], pp);
        Aa  *= s.a;
        Ba0 = fmaf(s.a, Ba0, s.b0);
        Ba1 = fmaf(s.a, Ba1, s.b1);
    }
    sum[(size_t)b * NCHUNK + c] = make_float4(Aa, Ba0, Ba1, 0.0f);
}

// Kernel 2: per-lane scan, single wave per block, zero barriers.
// block = lane (256 wgs), thread = 4 consecutive chunks.
// Loads 64B contiguous/thread, 6 shuffle-compose hops, 32B contiguous stores.
__global__ __launch_bounds__(SCANT) void k_scan(const float4* __restrict__ sum,
                                                float2* __restrict__ sin_) {
    const int L = blockIdx.x;
    const int i = threadIdx.x;       // owns chunks 4i .. 4i+3

    const float4* src = sum + (size_t)L * NCHUNK + FOLD * i;
    float4 m0 = src[0], m1 = src[1], m2 = src[2], m3 = src[3];

    // thread-local compose (ascending): M = m3 ∘ m2 ∘ m1 ∘ m0
    float A = m0.x, B0 = m0.y, B1 = m0.z;
    B0 = fmaf(m1.x, B0, m1.y); B1 = fmaf(m1.x, B1, m1.z); A *= m1.x;
    B0 = fmaf(m2.x, B0, m2.y); B1 = fmaf(m2.x, B1, m2.z); A *= m2.x;
    B0 = fmaf(m3.x, B0, m3.y); B1 = fmaf(m3.x, B1, m3.z); A *= m3.x;

    // inclusive wave scan (compose with earlier threads)
#pragma unroll
    for (int off = 1; off < SCANT; off <<= 1) {
        float pA  = __shfl_up(A,  off, SCANT);
        float pB0 = __shfl_up(B0, off, SCANT);
        float pB1 = __shfl_up(B1, off, SCANT);
        if (i >= off) {
            B0 = fmaf(A, pB0, B0);   // cur ∘ prev
            B1 = fmaf(A, pB1, B1);
            A  = A * pA;
        }
    }
    // exclusive prefix applied to s=0 -> incoming state of chunk 4i
    float eB0 = __shfl_up(B0, 1, SCANT);
    float eB1 = __shfl_up(B1, 1, SCANT);
    if (i == 0) { eB0 = 0.0f; eB1 = 0.0f; }

    float2* dst = sin_ + (size_t)L * NCHUNK + FOLD * i;
    dst[0] = make_float2(eB0, eB1);
    float s0 = fmaf(m0.x, eB0, m0.y), s1 = fmaf(m0.x, eB1, m0.z);
    dst[1] = make_float2(s0, s1);
    s0 = fmaf(m1.x, s0, m1.y); s1 = fmaf(m1.x, s1, m1.z);
    dst[2] = make_float2(s0, s1);
    s0 = fmaf(m2.x, s0, m2.y); s1 = fmaf(m2.x, s1, m2.z);
    dst[3] = make_float2(s0, s1);
}

// Kernel 3: read incoming state (scattered 8B load, L2/L3-resident),
// recompute the chunk's 16 steps, write q & logits coalesced.
__global__ __launch_bounds__(BKB) void k_apply(
    const float* __restrict__ obs, const float* __restrict__ W_in,
    const float* __restrict__ b_in, const float* __restrict__ W_inproj,
    const float* __restrict__ conv_w, const float* __restrict__ conv_b,
    const float* __restrict__ dt_bias, const float* __restrict__ A_log,
    const float* __restrict__ Dp_, const float* __restrict__ norm_w,
    const float* __restrict__ W_out, const float* __restrict__ head,
    const float* __restrict__ log_tau, const float2* __restrict__ sin_,
    float* __restrict__ out) {
    int b = threadIdx.x;
    int c = blockIdx.x;
    int t0 = c * TC;
    // issue the scattered state load first so it overlaps the uniform setup
    float2 sv = sin_[(size_t)b * NCHUNK + c];
    Pars p = load_pars(W_in, b_in, W_inproj, conv_w, conv_b, dt_bias, A_log);
    const float Dp = Dp_[0];
    const float w0 = (W_out[0] + W_out[2]) * norm_w[0];
    const float w1 = (W_out[1] + W_out[3]) * norm_w[1];
    const float hscale = softplus_f(head[0]);
    const float itau   = __expf(-log_tau[0]);

    float s0 = sv.x, s1 = sv.y;
    float pp[4];
    init_pp(p, obs, t0, b, pp);
#pragma unroll
    for (int i = 0; i < TC; ++i) {
        const int t = t0 + i;
        const float* op = obs + ((size_t)t * BKB + b) * OBSD;
        Step s = do_step(p, op[0], op[1], op[2], pp);
        s0 = fmaf(s.a, s0, s.b0);
        s1 = fmaf(s.a, s1, s.b1);
        float y0 = fmaf(s.Cv, s0, s.xh0 * Dp);
        float y1 = fmaf(s.Cv, s1, s.xh1 * Dp);
        y0 *= silu_f(s.z0);
        y1 *= silu_f(s.z1);
        float r = __builtin_amdgcn_rsqf(fmaf(0.5f, y0 * y0 + y1 * y1, EPSF));
        float q = (w0 * y0 + w1 * y1) * r * hscale;
        out[(size_t)t * BKB + b]       = q;
        out[TOT + (size_t)t * BKB + b] = q * itau;
    }
}

extern "C" void kernel_launch(void* const* d_in, const int* in_sizes, int n_in,
                              void* d_out, int out_size, void* d_ws, size_t ws_size,
                              hipStream_t stream) {
    const float* obs      = (const float*)d_in[0];
    const float* W_in     = (const float*)d_in[1];
    const float* b_in     = (const float*)d_in[2];
    const float* W_inproj = (const float*)d_in[3];
    const float* conv_w   = (const float*)d_in[4];
    const float* conv_b   = (const float*)d_in[5];
    const float* dt_bias  = (const float*)d_in[6];
    const float* A_log    = (const float*)d_in[7];
    const float* Dp       = (const float*)d_in[8];
    const float* norm_w   = (const float*)d_in[9];
    const float* W_out    = (const float*)d_in[10];
    const float* head     = (const float*)d_in[11];
    const float* log_tau  = (const float*)d_in[12];
    // d_in[13] = k (unused in compute)

    float4* sum  = (float4*)d_ws;                                   // 1 MB
    float2* sin_ = (float2*)((char*)d_ws + SUM_ELEMS * sizeof(float4)); // 0.5 MB
    float*  out  = (float*)d_out;

    k_summary<<<NCHUNK, BKB, 0, stream>>>(obs, W_in, b_in, W_inproj, conv_w, conv_b,
                                          dt_bias, A_log, sum);
    k_scan<<<BKB, SCANT, 0, stream>>>(sum, sin_);
    k_apply<<<NCHUNK, BKB, 0, stream>>>(obs, W_in, b_in, W_inproj, conv_w, conv_b,
                                        dt_bias, A_log, Dp, norm_w, W_out, head,
                                        log_tau, sin_, out);
}